// Round 3
// baseline (1619.919 us; speedup 1.0000x reference)
//
#include <hip/hip_runtime.h>
#include <stdint.h>
#include <math.h>

typedef __attribute__((ext_vector_type(8))) short short8;
typedef __attribute__((ext_vector_type(4))) short short4v;
typedef __attribute__((ext_vector_type(4))) float f32x4;

__device__ __forceinline__ short f2bf(float f){
  union { float f; uint32_t u; } x; x.f = f;
  uint32_t r = x.u + 0x7fffu + ((x.u >> 16) & 1u);
  return (short)(r >> 16);
}
__device__ __forceinline__ float bf2f(short s){
  union { uint32_t u; float f; } x; x.u = ((uint32_t)(uint16_t)s) << 16;
  return x.f;
}

// ---------------- prep kernels ----------------

// Transposed, bf16, concatenated weights: W3T[j][k], j in [0,4096), k in [0,3072)
// k<1024 -> Wx[k][j]; k<2048 -> Wh[k-1024][j]; else Wattn[k-2048][j]
__global__ __launch_bounds__(256) void k_wt(const float* __restrict__ Wx,
                                            const float* __restrict__ Wh,
                                            const float* __restrict__ Wattn,
                                            short* __restrict__ W3T){
  __shared__ float tile[64][65];
  int bk = blockIdx.x % 48, bj = blockIdx.x / 48;
  int tx = threadIdx.x & 63, ty = threadIdx.x >> 6;   // ty 0..3
  int k0 = bk * 64, j0 = bj * 64;
  #pragma unroll
  for (int i = 0; i < 16; ++i){
    int kk = ty * 16 + i;
    int k = k0 + kk;
    const float* src = (k < 1024) ? (Wx + (size_t)k * 4096)
                     : (k < 2048) ? (Wh + (size_t)(k - 1024) * 4096)
                                  : (Wattn + (size_t)(k - 2048) * 4096);
    tile[kk][tx] = src[j0 + tx];
  }
  __syncthreads();
  #pragma unroll
  for (int i = 0; i < 16; ++i){
    int jj = ty * 16 + i;
    W3T[(size_t)(j0 + jj) * 3072 + k0 + tx] = f2bf(tile[tx][jj]);
  }
}

__global__ __launch_bounds__(256) void k_cast(const float* __restrict__ in,
                                              short* __restrict__ out, int n4){
  int i = blockIdx.x * 256 + threadIdx.x;
  if (i >= n4) return;
  float4 v = ((const float4*)in)[i];
  short4v o; o[0] = f2bf(v.x); o[1] = f2bf(v.y); o[2] = f2bf(v.z); o[3] = f2bf(v.w);
  *(short4v*)(out + (size_t)i * 4) = o;
}

// h0 = c0 = mean over L=16 of A ; h0 into habuf parity 0
__global__ __launch_bounds__(256) void k_init(const float* __restrict__ A,
                                              float* __restrict__ c,
                                              short* __restrict__ hab0){
  int idx = blockIdx.x * 256 + threadIdx.x;    // N*H = 131072
  int n = idx >> 10, h = idx & 1023;
  const float* p = A + (size_t)idx * 16;
  float s = 0.f;
  #pragma unroll
  for (int l = 0; l < 16; ++l) s += p[l];
  s *= (1.f / 16.f);
  c[idx] = s;
  hab0[(size_t)n * 2048 + h] = f2bf(s);
}

// ---------------- per-step kernels ----------------

// One block per n. scores = (h . A[:,l]) / 32, softmax over 16,
// attn = A @ w -> bf16 into hab cols 1024..2047 (same parity buffer).
__global__ __launch_bounds__(256) void k_attn(const short* __restrict__ Abf,
                                              short* __restrict__ hab){
  const int n = blockIdx.x;
  const int tid = threadIdx.x;
  float sc[16];
  #pragma unroll
  for (int l = 0; l < 16; ++l) sc[l] = 0.f;
  #pragma unroll
  for (int m = 0; m < 4; ++m){
    int hh = tid + m * 256;
    float hv = bf2f(hab[(size_t)n * 2048 + hh]);
    const short8* ap = (const short8*)(Abf + ((size_t)n * 1024 + hh) * 16);
    short8 a0 = ap[0], a1 = ap[1];
    #pragma unroll
    for (int l = 0; l < 8; ++l){ sc[l] += hv * bf2f(a0[l]); sc[8+l] += hv * bf2f(a1[l]); }
  }
  #pragma unroll
  for (int off = 1; off < 64; off <<= 1)
    #pragma unroll
    for (int l = 0; l < 16; ++l) sc[l] += __shfl_xor(sc[l], off);
  __shared__ float sred[64];
  int w = tid >> 6, lane = tid & 63;
  if (lane == 0){
    #pragma unroll
    for (int l = 0; l < 16; ++l) sred[w * 16 + l] = sc[l];
  }
  __syncthreads();
  float s[16]; float mx = -1e30f;
  #pragma unroll
  for (int l = 0; l < 16; ++l){
    s[l] = (sred[l] + sred[16+l] + sred[32+l] + sred[48+l]) * 0.03125f;
    mx = fmaxf(mx, s[l]);
  }
  float sum = 0.f;
  #pragma unroll
  for (int l = 0; l < 16; ++l){ s[l] = expf(s[l] - mx); sum += s[l]; }
  float inv = 1.f / sum;
  #pragma unroll
  for (int l = 0; l < 16; ++l) s[l] *= inv;
  #pragma unroll
  for (int m = 0; m < 4; ++m){
    int hh = tid + m * 256;
    const short8* ap = (const short8*)(Abf + ((size_t)n * 1024 + hh) * 16);
    short8 a0 = ap[0], a1 = ap[1];
    float acc = 0.f;
    #pragma unroll
    for (int l = 0; l < 8; ++l){ acc += s[l] * bf2f(a0[l]); acc += s[8+l] * bf2f(a1[l]); }
    hab[(size_t)n * 2048 + 1024 + hh] = f2bf(acc);
  }
}

// Fused a = [x_t | h | attn] @ W3 (+b) -> gates -> LSTM update.
// 256 blocks x 8 waves; block tile = 32 n x 16 u x 4 gates; waves K-split 8-way
// (Kc=384 = 3 chunks of 128, whole-chunk bulk loads, double-buffered); LDS reduce.
// Reads hR (parity p), writes new h into hW (parity 1-p) -> no cross-block race.
__global__ __launch_bounds__(512, 2) void k_step2(
    const short* __restrict__ W3T,
    const short* __restrict__ xbf,
    const short* __restrict__ hR,
    short* __restrict__ hW,
    const float* __restrict__ bias,
    float* __restrict__ c,
    float* __restrict__ out,
    int t)
{
  __shared__ float red[8][2][4][64][4];   // 64 KB
  const int lane = threadIdx.x & 63;
  const int wave = threadIdx.x >> 6;      // 0..7
  const int bid = blockIdx.x;             // 256 blocks
  const int xcd = bid & 7;
  const int idx = bid >> 3;               // 0..31
  const int m0 = (idx & 3) * 32;
  const int u0 = (xcd * 8 + (idx >> 2)) * 16;
  const int ra = lane & 15;
  const int q  = lane >> 4;
  const int kw0 = wave * 384;             // per-wave K window [kw0, kw0+384)

  f32x4 acc[2][4];
  #pragma unroll
  for (int mf = 0; mf < 2; ++mf)
    #pragma unroll
    for (int g = 0; g < 4; ++g) acc[mf][g] = f32x4{0.f,0.f,0.f,0.f};

  auto loadA = [&](int gk, int mf, int i) -> short8 {
    int k = gk + i * 32 + q * 8;
    int row = m0 + mf * 16 + ra;
    const short* p = (gk < 1024)
        ? (xbf + (size_t)row * 65536 + t * 1024 + k)
        : (hR + (size_t)row * 2048 + (k - 1024));
    return *(const short8*)p;
  };
  auto loadB = [&](int gk, int g, int i) -> short8 {
    int k = gk + i * 32 + q * 8;
    return *(const short8*)(W3T + (size_t)(g * 1024 + u0 + ra) * 3072 + k);
  };

  short8 A0[2][4], B0[4][4], A1[2][4], B1[4][4];
  // chunk 0 -> buf0, chunk 1 -> buf1
  #pragma unroll
  for (int mf = 0; mf < 2; ++mf)
    #pragma unroll
    for (int i = 0; i < 4; ++i) A0[mf][i] = loadA(kw0, mf, i);
  #pragma unroll
  for (int g = 0; g < 4; ++g)
    #pragma unroll
    for (int i = 0; i < 4; ++i) B0[g][i] = loadB(kw0, g, i);
  #pragma unroll
  for (int mf = 0; mf < 2; ++mf)
    #pragma unroll
    for (int i = 0; i < 4; ++i) A1[mf][i] = loadA(kw0 + 128, mf, i);
  #pragma unroll
  for (int g = 0; g < 4; ++g)
    #pragma unroll
    for (int i = 0; i < 4; ++i) B1[g][i] = loadB(kw0 + 128, g, i);

  // MFMA chunk 0 (buf0)
  #pragma unroll
  for (int i = 0; i < 4; ++i)
    #pragma unroll
    for (int mf = 0; mf < 2; ++mf)
      #pragma unroll
      for (int g = 0; g < 4; ++g)
        acc[mf][g] = __builtin_amdgcn_mfma_f32_16x16x32_bf16(A0[mf][i], B0[g][i], acc[mf][g], 0, 0, 0);

  // chunk 2 -> buf0
  #pragma unroll
  for (int mf = 0; mf < 2; ++mf)
    #pragma unroll
    for (int i = 0; i < 4; ++i) A0[mf][i] = loadA(kw0 + 256, mf, i);
  #pragma unroll
  for (int g = 0; g < 4; ++g)
    #pragma unroll
    for (int i = 0; i < 4; ++i) B0[g][i] = loadB(kw0 + 256, g, i);

  // MFMA chunk 1 (buf1)
  #pragma unroll
  for (int i = 0; i < 4; ++i)
    #pragma unroll
    for (int mf = 0; mf < 2; ++mf)
      #pragma unroll
      for (int g = 0; g < 4; ++g)
        acc[mf][g] = __builtin_amdgcn_mfma_f32_16x16x32_bf16(A1[mf][i], B1[g][i], acc[mf][g], 0, 0, 0);

  // MFMA chunk 2 (buf0)
  #pragma unroll
  for (int i = 0; i < 4; ++i)
    #pragma unroll
    for (int mf = 0; mf < 2; ++mf)
      #pragma unroll
      for (int g = 0; g < 4; ++g)
        acc[mf][g] = __builtin_amdgcn_mfma_f32_16x16x32_bf16(A0[mf][i], B0[g][i], acc[mf][g], 0, 0, 0);

  // cross-wave reduction
  #pragma unroll
  for (int mf = 0; mf < 2; ++mf)
    #pragma unroll
    for (int g = 0; g < 4; ++g)
      *(f32x4*)&red[wave][mf][g][lane][0] = acc[mf][g];
  __syncthreads();

  if (wave < 2){
    const int mf = wave;
    f32x4 tot[4];
    #pragma unroll
    for (int g = 0; g < 4; ++g){
      f32x4 s = *(const f32x4*)&red[0][mf][g][lane][0];
      #pragma unroll
      for (int w = 1; w < 8; ++w) s += *(const f32x4*)&red[w][mf][g][lane][0];
      tot[g] = s;
    }
    const int u = u0 + ra;
    const float bi = bias[u], bfv = bias[1024 + u], bo = bias[2048 + u], bg = bias[3072 + u];
    #pragma unroll
    for (int i = 0; i < 4; ++i){
      int n = m0 + mf * 16 + q * 4 + i;
      float av = tot[0][i] + bi;
      float fv = tot[1][i] + bfv;
      float ov = tot[2][i] + bo;
      float gv = tot[3][i] + bg;
      float ig = 1.f / (1.f + expf(-av));
      float fg = 1.f / (1.f + expf(-fv));
      float og = 1.f / (1.f + expf(-ov));
      float gg = tanhf(gv);
      float cn = fg * c[(size_t)n * 1024 + u] + ig * gg;
      c[(size_t)n * 1024 + u] = cn;
      float hn = og * tanhf(cn);
      hW[(size_t)n * 2048 + u] = f2bf(hn);
      __builtin_nontemporal_store(hn, &out[((size_t)n * 64 + t) * 1024 + u]);
    }
  }
}

// ---------------- launch ----------------

extern "C" void kernel_launch(void* const* d_in, const int* in_sizes, int n_in,
                              void* d_out, int out_size, void* d_ws, size_t ws_size,
                              hipStream_t stream)
{
  const float* x     = (const float*)d_in[0];
  const float* A     = (const float*)d_in[1];
  const float* Wx    = (const float*)d_in[2];
  const float* Wh    = (const float*)d_in[3];
  const float* Wattn = (const float*)d_in[4];
  const float* b     = (const float*)d_in[5];
  float* out = (float*)d_out;
  char* ws = (char*)d_ws;

  short* W3T   = (short*)(ws + 0);            // 4096*3072*2  = 25165824
  short* Abf   = (short*)(ws + 25165824);     // 2097152*2    =  4194304
  short* xbf   = (short*)(ws + 29360128);     // 8388608*2    = 16777216
  short* habuf = (short*)(ws + 46137344);     // 2*128*2048*2 =  1048576
  float* cbuf  = (float*)(ws + 47185920);     // 128*1024*4   =   524288

  hipLaunchKernelGGL(k_wt,   dim3(48 * 64), dim3(256), 0, stream, Wx, Wh, Wattn, W3T);
  hipLaunchKernelGGL(k_cast, dim3(2097152 / 256), dim3(256), 0, stream, x, xbf, 2097152);
  hipLaunchKernelGGL(k_cast, dim3(524288 / 256),  dim3(256), 0, stream, A, Abf, 524288);
  hipLaunchKernelGGL(k_init, dim3(512), dim3(256), 0, stream, A, cbuf, habuf);

  for (int t = 0; t < 64; ++t){
    short* hR = habuf + (size_t)(t & 1) * 262144;
    short* hW = habuf + (size_t)((t + 1) & 1) * 262144;
    hipLaunchKernelGGL(k_attn,  dim3(128), dim3(256), 0, stream, Abf, hR);
    hipLaunchKernelGGL(k_step2, dim3(256), dim3(512), 0, stream,
                       W3T, xbf, hR, hW, b, cbuf, out, t);
  }
}